// Round 1
// baseline (843.446 us; speedup 1.0000x reference)
//
#include <hip/hip_runtime.h>
#include <math.h>

#define NN 50000
#define NE 800000
#define TE (NE + NN)
#define HC 128
#define NEG_SLOPE 0.2f
#define EPSV 1e-5f

// ---------------- CSR build ----------------

__global__ __launch_bounds__(256) void count_k(const int* __restrict__ dst, int* __restrict__ cnt) {
    int e = blockIdx.x * 256 + threadIdx.x;
    if (e >= TE) return;
    int d = (e < NE) ? dst[e] : (e - NE);
    atomicAdd(&cnt[d], 1);
}

__global__ __launch_bounds__(1024) void scan_k(const int* __restrict__ cnt,
                                               int* __restrict__ row_ptr,
                                               int* __restrict__ fill) {
    __shared__ int buf[1024];
    __shared__ int carry_s;
    int tid = threadIdx.x;
    if (tid == 0) carry_s = 0;
    __syncthreads();
    for (int base = 0; base < NN; base += 1024) {
        int v = (base + tid < NN) ? cnt[base + tid] : 0;
        buf[tid] = v;
        __syncthreads();
        for (int off = 1; off < 1024; off <<= 1) {
            int t = (tid >= off) ? buf[tid - off] : 0;
            __syncthreads();
            if (tid >= off) buf[tid] += t;
            __syncthreads();
        }
        int incl = buf[tid];
        int cb = carry_s;
        int excl = cb + incl - v;
        if (base + tid < NN) { row_ptr[base + tid] = excl; fill[base + tid] = excl; }
        int total = buf[1023];
        __syncthreads();
        if (tid == 0) carry_s = cb + total;
        __syncthreads();
    }
    if (tid == 0) row_ptr[NN] = TE;
}

__global__ __launch_bounds__(256) void scatter_k(const int* __restrict__ srcp,
                                                 const int* __restrict__ dstp,
                                                 int* __restrict__ fill,
                                                 int* __restrict__ col) {
    int e = blockIdx.x * 256 + threadIdx.x;
    if (e >= TE) return;
    int s, d;
    if (e < NE) { s = srcp[e]; d = dstp[e]; } else { s = e - NE; d = s; }
    int pos = atomicAdd(&fill[d], 1);
    col[pos] = s;
}

// ---------------- Dual GEMM: xl = x@Wl, xr = x@Wr ----------------
// x: (n,K) row-major, Wl/Wr: (K,128) row-major. Block computes 64 rows x 256 cols.
// 8x8 register tile per thread (8 rows x (4 xl cols + 4 xr cols)).

__global__ __launch_bounds__(256) void gemm_dual(const float* __restrict__ x,
                                                 const float* __restrict__ Wl,
                                                 const float* __restrict__ Wr,
                                                 float* __restrict__ xl,
                                                 float* __restrict__ xr,
                                                 int n, int K) {
    __shared__ float xs[32][72];    // [k][row], row-stride 72 floats (288B, 16B aligned)
    __shared__ float ws[32][260];   // [k][col 0..255], stride 260 floats (1040B, 16B aligned)
    int tid = threadIdx.x;
    int row0 = blockIdx.x * 64;
    int row_t = (tid >> 5) * 8;       // 0..56
    int c0 = (tid & 31) * 4;          // 0..124

    float acc0[8][4];
    float acc1[8][4];
#pragma unroll
    for (int i = 0; i < 8; ++i)
#pragma unroll
        for (int j = 0; j < 4; ++j) { acc0[i][j] = 0.f; acc1[i][j] = 0.f; }

    for (int k0 = 0; k0 < K; k0 += 32) {
        int kc = min(32, K - k0);
        // load x chunk (transposed into LDS)
        for (int i = tid; i < 64 * kc; i += 256) {
            int r = i / kc;
            int k = i - r * kc;
            int row = row0 + r;
            xs[k][r] = (row < n) ? x[(size_t)row * K + k0 + k] : 0.f;
        }
        // load W chunk (Wl cols 0..127, Wr cols 128..255)
        for (int i = tid; i < kc * 64; i += 256) {
            int k = i >> 6;
            int cq = i & 63;
            const float* srcp = (cq < 32) ? &Wl[(size_t)(k0 + k) * 128 + cq * 4]
                                          : &Wr[(size_t)(k0 + k) * 128 + (cq - 32) * 4];
            float4 v = *(const float4*)srcp;
            *(float4*)&ws[k][cq * 4] = v;
        }
        __syncthreads();
        for (int k = 0; k < kc; ++k) {
            float4 a0 = *(float4*)&xs[k][row_t];
            float4 a1 = *(float4*)&xs[k][row_t + 4];
            float4 b0 = *(float4*)&ws[k][c0];
            float4 b1 = *(float4*)&ws[k][c0 + 128];
            float av[8] = {a0.x, a0.y, a0.z, a0.w, a1.x, a1.y, a1.z, a1.w};
            float bl[4] = {b0.x, b0.y, b0.z, b0.w};
            float br[4] = {b1.x, b1.y, b1.z, b1.w};
#pragma unroll
            for (int i = 0; i < 8; ++i)
#pragma unroll
                for (int j = 0; j < 4; ++j) {
                    acc0[i][j] += av[i] * bl[j];
                    acc1[i][j] += av[i] * br[j];
                }
        }
        __syncthreads();
    }
#pragma unroll
    for (int i = 0; i < 8; ++i) {
        int row = row0 + row_t + i;
        if (row < n) {
            float4 o0; o0.x = acc0[i][0]; o0.y = acc0[i][1]; o0.z = acc0[i][2]; o0.w = acc0[i][3];
            float4 o1; o1.x = acc1[i][0]; o1.y = acc1[i][1]; o1.z = acc1[i][2]; o1.w = acc1[i][3];
            *(float4*)&xl[(size_t)row * HC + c0] = o0;
            *(float4*)&xr[(size_t)row * HC + c0] = o1;
        }
    }
}

// ---------------- Attention: one wave (64 lanes) per dst node ----------------

__global__ __launch_bounds__(256) void attn_k(const float* __restrict__ xl,
                                              const float* __restrict__ xr,
                                              const float* __restrict__ att,
                                              const float* __restrict__ bias,
                                              const int* __restrict__ row_ptr,
                                              const int* __restrict__ colidx,
                                              float* __restrict__ hout) {
    int lane = threadIdx.x & 63;
    int node = blockIdx.x * 4 + (threadIdx.x >> 6);
    if (node >= NN) return;

    float xr0 = xr[(size_t)node * HC + lane];
    float xr1 = xr[(size_t)node * HC + 64 + lane];
    float a0 = att[lane];
    float a1 = att[64 + lane];

    float m0 = -INFINITY, m1 = -INFINITY;
    float z0 = 0.f, z1 = 0.f, o0 = 0.f, o1 = 0.f;

    int beg = row_ptr[node];
    int end = row_ptr[node + 1];
    for (int idx = beg; idx < end; ++idx) {
        int s = colidx[idx];
        float l0 = xl[(size_t)s * HC + lane];
        float l1 = xl[(size_t)s * HC + 64 + lane];
        float e0 = l0 + xr0; e0 = (e0 > 0.f) ? e0 : NEG_SLOPE * e0;
        float e1 = l1 + xr1; e1 = (e1 > 0.f) ? e1 : NEG_SLOPE * e1;
        float v0 = a0 * e0;
        float v1 = a1 * e1;
#pragma unroll
        for (int off = 32; off > 0; off >>= 1) {
            v0 += __shfl_xor(v0, off, 64);
            v1 += __shfl_xor(v1, off, 64);
        }
        // v0, v1 are per-edge logits (uniform across wave)
        float nm0 = fmaxf(m0, v0);
        float sc0 = __expf(m0 - nm0);
        float p0 = __expf(v0 - nm0);
        z0 = z0 * sc0 + p0;
        o0 = o0 * sc0 + p0 * l0;
        m0 = nm0;

        float nm1 = fmaxf(m1, v1);
        float sc1 = __expf(m1 - nm1);
        float p1 = __expf(v1 - nm1);
        z1 = z1 * sc1 + p1;
        o1 = o1 * sc1 + p1 * l1;
        m1 = nm1;
    }
    float res = 0.5f * (o0 / z0 + o1 / z1) + bias[lane];
    hout[(size_t)node * 64 + lane] = res;
}

// ---------------- GraphNorm ----------------

__global__ __launch_bounds__(256) void colstats_k(const float* __restrict__ h,
                                                  float* __restrict__ stats) {
    int c = threadIdx.x & 63;
    int rg = threadIdx.x >> 6;
    float s = 0.f, s2 = 0.f;
    for (int r = blockIdx.x * 4 + rg; r < NN; r += gridDim.x * 4) {
        float v = h[(size_t)r * 64 + c];
        s += v;
        s2 += v * v;
    }
    __shared__ float b1[4][64];
    __shared__ float b2[4][64];
    b1[rg][c] = s;
    b2[rg][c] = s2;
    __syncthreads();
    if (threadIdx.x < 64) {
        s = b1[0][c] + b1[1][c] + b1[2][c] + b1[3][c];
        s2 = b2[0][c] + b2[1][c] + b2[2][c] + b2[3][c];
        atomicAdd(&stats[c], s);
        atomicAdd(&stats[64 + c], s2);
    }
}

__global__ __launch_bounds__(64) void coef_k(const float* __restrict__ stats,
                                             const float* __restrict__ gw,
                                             const float* __restrict__ gb,
                                             const float* __restrict__ gm,
                                             float* __restrict__ cf) {
    int c = threadIdx.x;
    float inv_n = 1.f / (float)NN;
    float mu = stats[c] * inv_n;
    float ex2 = stats[64 + c] * inv_n;
    float g = gm[c];
    float var = ex2 - 2.f * g * mu * mu + g * g * mu * mu;
    float rs = rsqrtf(var + EPSV);
    cf[c] = gw[c] * rs;
    cf[64 + c] = gb[c] - gw[c] * rs * g * mu;
}

__global__ __launch_bounds__(256) void apply_k(const float* __restrict__ h,
                                               const float* __restrict__ cf,
                                               float* __restrict__ y) {
    int i = blockIdx.x * 256 + threadIdx.x;
    if (i >= NN * 64) return;
    int c = i & 63;
    float v = cf[c] * h[i] + cf[64 + c];
    y[i] = (v > 0.f) ? v : 0.f;
}

// ---------------- launch ----------------

extern "C" void kernel_launch(void* const* d_in, const int* in_sizes, int n_in,
                              void* d_out, int out_size, void* d_ws, size_t ws_size,
                              hipStream_t stream) {
    const float* x0 = (const float*)d_in[0];
    const int* ei = (const int*)d_in[1];
    const int* srcp = ei;        // edge_index[0]
    const int* dstp = ei + NE;   // edge_index[1]

    const float* Wl[3], *Wr[3], *att[3], *bv[3], *gw[3], *gb[3], *gm[3];
    for (int l = 0; l < 3; ++l) {
        int base = 2 + 7 * l;
        Wl[l] = (const float*)d_in[base + 0];
        Wr[l] = (const float*)d_in[base + 1];
        att[l] = (const float*)d_in[base + 2];
        bv[l] = (const float*)d_in[base + 3];
        gw[l] = (const float*)d_in[base + 4];
        gb[l] = (const float*)d_in[base + 5];
        gm[l] = (const float*)d_in[base + 6];
    }

    char* p = (char*)d_ws;
    auto take = [&](size_t bytes) -> void* {
        void* r = (void*)p;
        p += (bytes + 255) & ~(size_t)255;
        return r;
    };
    float* xl = (float*)take((size_t)NN * 128 * 4);
    float* xr = (float*)take((size_t)NN * 128 * 4);
    float* hb = (float*)take((size_t)NN * 64 * 4);
    float* xc = (float*)take((size_t)NN * 64 * 4);
    int* cnt = (int*)take((size_t)NN * 4);
    int* row_ptr = (int*)take((size_t)(NN + 1) * 4);
    int* fill = (int*)take((size_t)NN * 4);
    int* col = (int*)take((size_t)TE * 4);
    float* stats = (float*)take(128 * 4);
    float* cf = (float*)take(128 * 4);

    // CSR build (edges are layer-invariant)
    hipMemsetAsync(cnt, 0, (size_t)NN * 4, stream);
    int egrid = (TE + 255) / 256;
    count_k<<<egrid, 256, 0, stream>>>(dstp, cnt);
    scan_k<<<1, 1024, 0, stream>>>(cnt, row_ptr, fill);
    scatter_k<<<egrid, 256, 0, stream>>>(srcp, dstp, fill, col);

    const float* xin = x0;
    int K = 3;
    int ggrid = (NN + 63) / 64;
    for (int l = 0; l < 3; ++l) {
        gemm_dual<<<ggrid, 256, 0, stream>>>(xin, Wl[l], Wr[l], xl, xr, NN, K);
        attn_k<<<NN / 4, 256, 0, stream>>>(xl, xr, att[l], bv[l], row_ptr, col, hb);
        hipMemsetAsync(stats, 0, 512, stream);
        colstats_k<<<256, 256, 0, stream>>>(hb, stats);
        coef_k<<<1, 64, 0, stream>>>(stats, gw[l], gb[l], gm[l], cf);
        float* y = (l == 2) ? (float*)d_out : xc;
        apply_k<<<(NN * 64 + 255) / 256, 256, 0, stream>>>(hb, cf, y);
        xin = xc;
        K = 64;
    }
}

// Round 2
// 616.228 us; speedup vs baseline: 1.3687x; 1.3687x over previous
//
#include <hip/hip_runtime.h>
#include <math.h>

#define NN 50000
#define NE 800000
#define TE (NE + NN)
#define HC 128
#define NEG_SLOPE 0.2f
#define EPSV 1e-5f

// ---------------- CSR build ----------------

__global__ __launch_bounds__(256) void count_k(const int* __restrict__ dst, int* __restrict__ cnt) {
    int e = blockIdx.x * 256 + threadIdx.x;
    if (e >= TE) return;
    int d = (e < NE) ? dst[e] : (e - NE);
    atomicAdd(&cnt[d], 1);
}

// hierarchical scan: scan1 (per-block excl scan + block totals) -> scan2 (aux scan) -> scan3 (add)
__global__ __launch_bounds__(1024) void scan1_k(const int* __restrict__ cnt,
                                                int* __restrict__ excl,
                                                int* __restrict__ aux) {
    __shared__ int wsum[16];
    int tid = threadIdx.x;
    int gid = blockIdx.x * 1024 + tid;
    int lane = tid & 63, wid = tid >> 6;
    int v = (gid < NN) ? cnt[gid] : 0;
    int x = v;
#pragma unroll
    for (int off = 1; off < 64; off <<= 1) {
        int t = __shfl_up(x, off, 64);
        if (lane >= off) x += t;
    }
    if (lane == 63) wsum[wid] = x;
    __syncthreads();
    if (wid == 0 && lane < 16) {
        int y = wsum[lane];
#pragma unroll
        for (int off = 1; off < 16; off <<= 1) {
            int t = __shfl_up(y, off, 64);
            if (lane >= off) y += t;
        }
        wsum[lane] = y;
    }
    __syncthreads();
    int base = (wid > 0) ? wsum[wid - 1] : 0;
    int incl = base + x;
    if (gid < NN) excl[gid] = incl - v;
    if (tid == 1023) aux[blockIdx.x] = incl;
}

__global__ __launch_bounds__(64) void scan2_k(int* __restrict__ aux, int nblk) {
    int lane = threadIdx.x;
    int v = (lane < nblk) ? aux[lane] : 0;
    int x = v;
#pragma unroll
    for (int off = 1; off < 64; off <<= 1) {
        int t = __shfl_up(x, off, 64);
        if (lane >= off) x += t;
    }
    if (lane < nblk) aux[lane] = x - v;
}

__global__ __launch_bounds__(1024) void scan3_k(int* __restrict__ row_ptr,
                                               const int* __restrict__ aux,
                                               int* __restrict__ fill) {
    int gid = blockIdx.x * 1024 + threadIdx.x;
    if (gid < NN) {
        int r = row_ptr[gid] + aux[blockIdx.x];
        row_ptr[gid] = r;
        fill[gid] = r;
    }
    if (gid == 0) row_ptr[NN] = TE;
}

__global__ __launch_bounds__(256) void scatter_k(const int* __restrict__ srcp,
                                                 const int* __restrict__ dstp,
                                                 int* __restrict__ fill,
                                                 int* __restrict__ col) {
    int e = blockIdx.x * 256 + threadIdx.x;
    if (e >= TE) return;
    int s, d;
    if (e < NE) { s = srcp[e]; d = dstp[e]; } else { s = e - NE; d = s; }
    int pos = atomicAdd(&fill[d], 1);
    col[pos] = s;
}

// ---------------- Dual GEMM: xl = x@Wl, xr = x@Wr ----------------

__global__ __launch_bounds__(256) void gemm_dual(const float* __restrict__ x,
                                                 const float* __restrict__ Wl,
                                                 const float* __restrict__ Wr,
                                                 float* __restrict__ xl,
                                                 float* __restrict__ xr,
                                                 int n, int K) {
    __shared__ float xs[32][72];
    __shared__ float ws[32][260];
    int tid = threadIdx.x;
    int row0 = blockIdx.x * 64;
    int row_t = (tid >> 5) * 8;
    int c0 = (tid & 31) * 4;

    float acc0[8][4];
    float acc1[8][4];
#pragma unroll
    for (int i = 0; i < 8; ++i)
#pragma unroll
        for (int j = 0; j < 4; ++j) { acc0[i][j] = 0.f; acc1[i][j] = 0.f; }

    for (int k0 = 0; k0 < K; k0 += 32) {
        int kc = min(32, K - k0);
        for (int i = tid; i < 64 * kc; i += 256) {
            int r = i / kc;
            int k = i - r * kc;
            int row = row0 + r;
            xs[k][r] = (row < n) ? x[(size_t)row * K + k0 + k] : 0.f;
        }
        for (int i = tid; i < kc * 64; i += 256) {
            int k = i >> 6;
            int cq = i & 63;
            const float* srcp = (cq < 32) ? &Wl[(size_t)(k0 + k) * 128 + cq * 4]
                                          : &Wr[(size_t)(k0 + k) * 128 + (cq - 32) * 4];
            float4 v = *(const float4*)srcp;
            *(float4*)&ws[k][cq * 4] = v;
        }
        __syncthreads();
        for (int k = 0; k < kc; ++k) {
            float4 a0 = *(float4*)&xs[k][row_t];
            float4 a1 = *(float4*)&xs[k][row_t + 4];
            float4 b0 = *(float4*)&ws[k][c0];
            float4 b1 = *(float4*)&ws[k][c0 + 128];
            float av[8] = {a0.x, a0.y, a0.z, a0.w, a1.x, a1.y, a1.z, a1.w};
            float bl[4] = {b0.x, b0.y, b0.z, b0.w};
            float br[4] = {b1.x, b1.y, b1.z, b1.w};
#pragma unroll
            for (int i = 0; i < 8; ++i)
#pragma unroll
                for (int j = 0; j < 4; ++j) {
                    acc0[i][j] += av[i] * bl[j];
                    acc1[i][j] += av[i] * br[j];
                }
        }
        __syncthreads();
    }
#pragma unroll
    for (int i = 0; i < 8; ++i) {
        int row = row0 + row_t + i;
        if (row < n) {
            float4 o0; o0.x = acc0[i][0]; o0.y = acc0[i][1]; o0.z = acc0[i][2]; o0.w = acc0[i][3];
            float4 o1; o1.x = acc1[i][0]; o1.y = acc1[i][1]; o1.z = acc1[i][2]; o1.w = acc1[i][3];
            *(float4*)&xl[(size_t)row * HC + c0] = o0;
            *(float4*)&xr[(size_t)row * HC + c0] = o1;
        }
    }
}

// ---------------- Attention: one wave per dst node, 4-edge ILP, 8 shfl/edge ----------------

__global__ __launch_bounds__(256) void attn_k(const float* __restrict__ xl,
                                              const float* __restrict__ xr,
                                              const float* __restrict__ att,
                                              const float* __restrict__ bias,
                                              const int* __restrict__ row_ptr,
                                              const int* __restrict__ colidx,
                                              float* __restrict__ hout) {
    int lane = threadIdx.x & 63;
    int node = blockIdx.x * 4 + (threadIdx.x >> 6);
    if (node >= NN) return;
    bool lo = lane < 32;

    float xr0 = xr[(size_t)node * HC + lane];
    float xr1 = xr[(size_t)node * HC + 64 + lane];
    float a0 = att[lane];
    float a1 = att[64 + lane];

    float m0 = -INFINITY, m1 = -INFINITY;
    float z0 = 0.f, z1 = 0.f, o0 = 0.f, o1 = 0.f;

    int beg = row_ptr[node];
    int end = row_ptr[node + 1];
    int idx = beg;
    for (; idx + 4 <= end; idx += 4) {
        int s[4];
#pragma unroll
        for (int j = 0; j < 4; ++j) s[j] = colidx[idx + j];
        float l0[4], l1[4], u[4];
#pragma unroll
        for (int j = 0; j < 4; ++j) {
            l0[j] = xl[(size_t)s[j] * HC + lane];
            l1[j] = xl[(size_t)s[j] * HC + 64 + lane];
        }
#pragma unroll
        for (int j = 0; j < 4; ++j) {
            float e0 = l0[j] + xr0; e0 = (e0 > 0.f) ? e0 : NEG_SLOPE * e0;
            float e1 = l1[j] + xr1; e1 = (e1 > 0.f) ? e1 : NEG_SLOPE * e1;
            float v0 = a0 * e0;
            float v1 = a1 * e1;
            float t0 = __shfl_xor(v0, 32, 64);
            float t1 = __shfl_xor(v1, 32, 64);
            u[j] = lo ? (v0 + t0) : (v1 + t1);
        }
#pragma unroll
        for (int off = 16; off > 0; off >>= 1) {
#pragma unroll
            for (int j = 0; j < 4; ++j) u[j] += __shfl_xor(u[j], off, 64);
        }
#pragma unroll
        for (int j = 0; j < 4; ++j) {
            float t = __shfl_xor(u[j], 32, 64);
            float v0 = lo ? u[j] : t;
            float v1 = lo ? t : u[j];
            float nm0 = fmaxf(m0, v0);
            float sc0 = __expf(m0 - nm0);
            float p0 = __expf(v0 - nm0);
            z0 = z0 * sc0 + p0;
            o0 = o0 * sc0 + p0 * l0[j];
            m0 = nm0;
            float nm1 = fmaxf(m1, v1);
            float sc1 = __expf(m1 - nm1);
            float p1 = __expf(v1 - nm1);
            z1 = z1 * sc1 + p1;
            o1 = o1 * sc1 + p1 * l1[j];
            m1 = nm1;
        }
    }
    for (; idx < end; ++idx) {
        int s = colidx[idx];
        float l0 = xl[(size_t)s * HC + lane];
        float l1 = xl[(size_t)s * HC + 64 + lane];
        float e0 = l0 + xr0; e0 = (e0 > 0.f) ? e0 : NEG_SLOPE * e0;
        float e1 = l1 + xr1; e1 = (e1 > 0.f) ? e1 : NEG_SLOPE * e1;
        float v0p = a0 * e0;
        float v1p = a1 * e1;
        float t0 = __shfl_xor(v0p, 32, 64);
        float t1 = __shfl_xor(v1p, 32, 64);
        float u = lo ? (v0p + t0) : (v1p + t1);
#pragma unroll
        for (int off = 16; off > 0; off >>= 1) u += __shfl_xor(u, off, 64);
        float t = __shfl_xor(u, 32, 64);
        float v0 = lo ? u : t;
        float v1 = lo ? t : u;
        float nm0 = fmaxf(m0, v0);
        float sc0 = __expf(m0 - nm0);
        float p0 = __expf(v0 - nm0);
        z0 = z0 * sc0 + p0;
        o0 = o0 * sc0 + p0 * l0;
        m0 = nm0;
        float nm1 = fmaxf(m1, v1);
        float sc1 = __expf(m1 - nm1);
        float p1 = __expf(v1 - nm1);
        z1 = z1 * sc1 + p1;
        o1 = o1 * sc1 + p1 * l1;
        m1 = nm1;
    }
    float res = 0.5f * (o0 / z0 + o1 / z1) + bias[lane];
    hout[(size_t)node * 64 + lane] = res;
}

// ---------------- GraphNorm ----------------

__global__ __launch_bounds__(256) void colstats_k(const float* __restrict__ h,
                                                  float* __restrict__ stats) {
    int c = threadIdx.x & 63;
    int rg = threadIdx.x >> 6;
    float s = 0.f, s2 = 0.f;
    for (int r = blockIdx.x * 4 + rg; r < NN; r += gridDim.x * 4) {
        float v = h[(size_t)r * 64 + c];
        s += v;
        s2 += v * v;
    }
    __shared__ float b1[4][64];
    __shared__ float b2[4][64];
    b1[rg][c] = s;
    b2[rg][c] = s2;
    __syncthreads();
    if (threadIdx.x < 64) {
        s = b1[0][c] + b1[1][c] + b1[2][c] + b1[3][c];
        s2 = b2[0][c] + b2[1][c] + b2[2][c] + b2[3][c];
        atomicAdd(&stats[c], s);
        atomicAdd(&stats[64 + c], s2);
    }
}

__global__ __launch_bounds__(64) void coef_k(const float* __restrict__ stats,
                                             const float* __restrict__ gw,
                                             const float* __restrict__ gb,
                                             const float* __restrict__ gm,
                                             float* __restrict__ cf) {
    int c = threadIdx.x;
    float inv_n = 1.f / (float)NN;
    float mu = stats[c] * inv_n;
    float ex2 = stats[64 + c] * inv_n;
    float g = gm[c];
    float var = ex2 - 2.f * g * mu * mu + g * g * mu * mu;
    float rs = rsqrtf(var + EPSV);
    cf[c] = gw[c] * rs;
    cf[64 + c] = gb[c] - gw[c] * rs * g * mu;
}

__global__ __launch_bounds__(256) void apply_k(const float* __restrict__ h,
                                               const float* __restrict__ cf,
                                               float* __restrict__ y) {
    int i = blockIdx.x * 256 + threadIdx.x;
    if (i >= NN * 64) return;
    int c = i & 63;
    float v = cf[c] * h[i] + cf[64 + c];
    y[i] = (v > 0.f) ? v : 0.f;
}

// ---------------- launch ----------------

extern "C" void kernel_launch(void* const* d_in, const int* in_sizes, int n_in,
                              void* d_out, int out_size, void* d_ws, size_t ws_size,
                              hipStream_t stream) {
    const float* x0 = (const float*)d_in[0];
    const int* ei = (const int*)d_in[1];
    const int* srcp = ei;
    const int* dstp = ei + NE;

    const float* Wl[3], *Wr[3], *att[3], *bv[3], *gw[3], *gb[3], *gm[3];
    for (int l = 0; l < 3; ++l) {
        int base = 2 + 7 * l;
        Wl[l] = (const float*)d_in[base + 0];
        Wr[l] = (const float*)d_in[base + 1];
        att[l] = (const float*)d_in[base + 2];
        bv[l] = (const float*)d_in[base + 3];
        gw[l] = (const float*)d_in[base + 4];
        gb[l] = (const float*)d_in[base + 5];
        gm[l] = (const float*)d_in[base + 6];
    }

    char* p = (char*)d_ws;
    auto take = [&](size_t bytes) -> void* {
        void* r = (void*)p;
        p += (bytes + 255) & ~(size_t)255;
        return r;
    };
    float* xl = (float*)take((size_t)NN * 128 * 4);
    float* xr = (float*)take((size_t)NN * 128 * 4);
    float* hb = (float*)take((size_t)NN * 64 * 4);
    float* xc = (float*)take((size_t)NN * 64 * 4);
    int* cnt = (int*)take((size_t)NN * 4);
    int* row_ptr = (int*)take((size_t)(NN + 1) * 4);
    int* fill = (int*)take((size_t)NN * 4);
    int* col = (int*)take((size_t)TE * 4);
    int* aux = (int*)take(64 * 4);
    float* stats = (float*)take(128 * 4);
    float* cf = (float*)take(128 * 4);

    int nblk = (NN + 1023) / 1024;  // 49
    hipMemsetAsync(cnt, 0, (size_t)NN * 4, stream);
    int egrid = (TE + 255) / 256;
    count_k<<<egrid, 256, 0, stream>>>(dstp, cnt);
    scan1_k<<<nblk, 1024, 0, stream>>>(cnt, row_ptr, aux);
    scan2_k<<<1, 64, 0, stream>>>(aux, nblk);
    scan3_k<<<nblk, 1024, 0, stream>>>(row_ptr, aux, fill);
    scatter_k<<<egrid, 256, 0, stream>>>(srcp, dstp, fill, col);

    const float* xin = x0;
    int K = 3;
    int ggrid = (NN + 63) / 64;
    for (int l = 0; l < 3; ++l) {
        gemm_dual<<<ggrid, 256, 0, stream>>>(xin, Wl[l], Wr[l], xl, xr, NN, K);
        attn_k<<<(NN + 3) / 4, 256, 0, stream>>>(xl, xr, att[l], bv[l], row_ptr, col, hb);
        hipMemsetAsync(stats, 0, 512, stream);
        colstats_k<<<256, 256, 0, stream>>>(hb, stats);
        coef_k<<<1, 64, 0, stream>>>(stats, gw[l], gb[l], gm[l], cf);
        float* y = (l == 2) ? (float*)d_out : xc;
        apply_k<<<(NN * 64 + 255) / 256, 256, 0, stream>>>(hb, cf, y);
        xin = xc;
        K = 64;
    }
}

// Round 3
// 590.929 us; speedup vs baseline: 1.4273x; 1.0428x over previous
//
#include <hip/hip_runtime.h>
#include <math.h>

#define NN 50000
#define NE 800000
#define TE (NE + NN)
#define HC 128
#define NEG_SLOPE 0.2f
#define EPSV 1e-5f
#define STATS_BLOCKS 256

// ---------------- CSR build ----------------

__global__ __launch_bounds__(256) void count_k(const int* __restrict__ dst, int* __restrict__ cnt) {
    int e = blockIdx.x * 256 + threadIdx.x;
    if (e >= TE) return;
    int d = (e < NE) ? dst[e] : (e - NE);
    atomicAdd(&cnt[d], 1);
}

__global__ __launch_bounds__(1024) void scan1_k(const int* __restrict__ cnt,
                                                int* __restrict__ excl,
                                                int* __restrict__ aux) {
    __shared__ int wsum[16];
    int tid = threadIdx.x;
    int gid = blockIdx.x * 1024 + tid;
    int lane = tid & 63, wid = tid >> 6;
    int v = (gid < NN) ? cnt[gid] : 0;
    int x = v;
#pragma unroll
    for (int off = 1; off < 64; off <<= 1) {
        int t = __shfl_up(x, off, 64);
        if (lane >= off) x += t;
    }
    if (lane == 63) wsum[wid] = x;
    __syncthreads();
    if (wid == 0 && lane < 16) {
        int y = wsum[lane];
#pragma unroll
        for (int off = 1; off < 16; off <<= 1) {
            int t = __shfl_up(y, off, 64);
            if (lane >= off) y += t;
        }
        wsum[lane] = y;
    }
    __syncthreads();
    int base = (wid > 0) ? wsum[wid - 1] : 0;
    int incl = base + x;
    if (gid < NN) excl[gid] = incl - v;
    if (tid == 1023) aux[blockIdx.x] = incl;
}

__global__ __launch_bounds__(64) void scan2_k(int* __restrict__ aux, int nblk) {
    int lane = threadIdx.x;
    int v = (lane < nblk) ? aux[lane] : 0;
    int x = v;
#pragma unroll
    for (int off = 1; off < 64; off <<= 1) {
        int t = __shfl_up(x, off, 64);
        if (lane >= off) x += t;
    }
    if (lane < nblk) aux[lane] = x - v;
}

__global__ __launch_bounds__(1024) void scan3_k(int* __restrict__ row_ptr,
                                               const int* __restrict__ aux,
                                               int* __restrict__ fill) {
    int gid = blockIdx.x * 1024 + threadIdx.x;
    if (gid < NN) {
        int r = row_ptr[gid] + aux[blockIdx.x];
        row_ptr[gid] = r;
        fill[gid] = r;
    }
    if (gid == 0) row_ptr[NN] = TE;
}

__global__ __launch_bounds__(256) void scatter_k(const int* __restrict__ srcp,
                                                 const int* __restrict__ dstp,
                                                 int* __restrict__ fill,
                                                 int* __restrict__ col) {
    int e = blockIdx.x * 256 + threadIdx.x;
    if (e >= TE) return;
    int s, d;
    if (e < NE) { s = srcp[e]; d = dstp[e]; } else { s = e - NE; d = s; }
    int pos = atomicAdd(&fill[d], 1);
    col[pos] = s;
}

// ---------------- Dual GEMM (layer 1, raw x input) ----------------

__global__ __launch_bounds__(256) void gemm_dual(const float* __restrict__ x,
                                                 const float* __restrict__ Wl,
                                                 const float* __restrict__ Wr,
                                                 float* __restrict__ xl,
                                                 float* __restrict__ xr,
                                                 int n, int K) {
    __shared__ float xs[32][72];
    __shared__ float ws[32][260];
    int tid = threadIdx.x;
    int row0 = blockIdx.x * 64;
    int row_t = (tid >> 5) * 8;
    int c0 = (tid & 31) * 4;

    float acc0[8][4];
    float acc1[8][4];
#pragma unroll
    for (int i = 0; i < 8; ++i)
#pragma unroll
        for (int j = 0; j < 4; ++j) { acc0[i][j] = 0.f; acc1[i][j] = 0.f; }

    for (int k0 = 0; k0 < K; k0 += 32) {
        int kc = min(32, K - k0);
        for (int i = tid; i < 64 * kc; i += 256) {
            int r = i / kc;
            int k = i - r * kc;
            int row = row0 + r;
            xs[k][r] = (row < n) ? x[(size_t)row * K + k0 + k] : 0.f;
        }
        for (int i = tid; i < kc * 64; i += 256) {
            int k = i >> 6;
            int cq = i & 63;
            const float* srcp = (cq < 32) ? &Wl[(size_t)(k0 + k) * 128 + cq * 4]
                                          : &Wr[(size_t)(k0 + k) * 128 + (cq - 32) * 4];
            float4 v = *(const float4*)srcp;
            *(float4*)&ws[k][cq * 4] = v;
        }
        __syncthreads();
        for (int k = 0; k < kc; ++k) {
            float4 a0 = *(float4*)&xs[k][row_t];
            float4 a1 = *(float4*)&xs[k][row_t + 4];
            float4 b0 = *(float4*)&ws[k][c0];
            float4 b1 = *(float4*)&ws[k][c0 + 128];
            float av[8] = {a0.x, a0.y, a0.z, a0.w, a1.x, a1.y, a1.z, a1.w};
            float bl[4] = {b0.x, b0.y, b0.z, b0.w};
            float br[4] = {b1.x, b1.y, b1.z, b1.w};
#pragma unroll
            for (int i = 0; i < 8; ++i)
#pragma unroll
                for (int j = 0; j < 4; ++j) {
                    acc0[i][j] += av[i] * bl[j];
                    acc1[i][j] += av[i] * br[j];
                }
        }
        __syncthreads();
    }
#pragma unroll
    for (int i = 0; i < 8; ++i) {
        int row = row0 + row_t + i;
        if (row < n) {
            float4 o0; o0.x = acc0[i][0]; o0.y = acc0[i][1]; o0.z = acc0[i][2]; o0.w = acc0[i][3];
            float4 o1; o1.x = acc1[i][0]; o1.y = acc1[i][1]; o1.z = acc1[i][2]; o1.w = acc1[i][3];
            *(float4*)&xl[(size_t)row * HC + c0] = o0;
            *(float4*)&xr[(size_t)row * HC + c0] = o1;
        }
    }
}

// ---------------- Dual GEMM with fused graph-norm + ReLU on the input ----------------
// x_eff[r][k] = relu(cf[k]*h[r][k] + cf[64+k]),  K = 64 fixed.

__global__ __launch_bounds__(256) void gemm_fused(const float* __restrict__ h,
                                                  const float* __restrict__ cf,
                                                  const float* __restrict__ Wl,
                                                  const float* __restrict__ Wr,
                                                  float* __restrict__ xl,
                                                  float* __restrict__ xr,
                                                  int n) {
    __shared__ float xs[32][72];
    __shared__ float ws[32][260];
    int tid = threadIdx.x;
    int row0 = blockIdx.x * 64;
    int row_t = (tid >> 5) * 8;
    int c0 = (tid & 31) * 4;

    float acc0[8][4];
    float acc1[8][4];
#pragma unroll
    for (int i = 0; i < 8; ++i)
#pragma unroll
        for (int j = 0; j < 4; ++j) { acc0[i][j] = 0.f; acc1[i][j] = 0.f; }

    for (int k0 = 0; k0 < 64; k0 += 32) {
        for (int i = tid; i < 64 * 32; i += 256) {
            int r = i >> 5;
            int k = i & 31;
            int row = row0 + r;
            float v = 0.f;
            if (row < n) {
                v = h[(size_t)row * 64 + k0 + k];
                v = fmaf(cf[k0 + k], v, cf[64 + k0 + k]);
                v = fmaxf(v, 0.f);
            }
            xs[k][r] = v;
        }
        for (int i = tid; i < 32 * 64; i += 256) {
            int k = i >> 6;
            int cq = i & 63;
            const float* srcp = (cq < 32) ? &Wl[(size_t)(k0 + k) * 128 + cq * 4]
                                          : &Wr[(size_t)(k0 + k) * 128 + (cq - 32) * 4];
            float4 v = *(const float4*)srcp;
            *(float4*)&ws[k][cq * 4] = v;
        }
        __syncthreads();
        for (int k = 0; k < 32; ++k) {
            float4 a0 = *(float4*)&xs[k][row_t];
            float4 a1 = *(float4*)&xs[k][row_t + 4];
            float4 b0 = *(float4*)&ws[k][c0];
            float4 b1 = *(float4*)&ws[k][c0 + 128];
            float av[8] = {a0.x, a0.y, a0.z, a0.w, a1.x, a1.y, a1.z, a1.w};
            float bl[4] = {b0.x, b0.y, b0.z, b0.w};
            float br[4] = {b1.x, b1.y, b1.z, b1.w};
#pragma unroll
            for (int i = 0; i < 8; ++i)
#pragma unroll
                for (int j = 0; j < 4; ++j) {
                    acc0[i][j] += av[i] * bl[j];
                    acc1[i][j] += av[i] * br[j];
                }
        }
        __syncthreads();
    }
#pragma unroll
    for (int i = 0; i < 8; ++i) {
        int row = row0 + row_t + i;
        if (row < n) {
            float4 o0; o0.x = acc0[i][0]; o0.y = acc0[i][1]; o0.z = acc0[i][2]; o0.w = acc0[i][3];
            float4 o1; o1.x = acc1[i][0]; o1.y = acc1[i][1]; o1.z = acc1[i][2]; o1.w = acc1[i][3];
            *(float4*)&xl[(size_t)row * HC + c0] = o0;
            *(float4*)&xr[(size_t)row * HC + c0] = o1;
        }
    }
}

// ---------------- Attention: one wave per dst node, packed 4-edge reduction ----------------

__global__ __launch_bounds__(256) void attn_k(const float* __restrict__ xl,
                                              const float* __restrict__ xr,
                                              const float* __restrict__ att,
                                              const float* __restrict__ bias,
                                              const int* __restrict__ row_ptr,
                                              const int* __restrict__ colidx,
                                              float* __restrict__ hout) {
    int lane = threadIdx.x & 63;
    int node = blockIdx.x * 4 + (threadIdx.x >> 6);
    if (node >= NN) return;
    bool lo = lane < 32;
    bool g16 = (lane & 16) == 0;

    float xr0 = xr[(size_t)node * HC + lane];
    float xr1 = xr[(size_t)node * HC + 64 + lane];
    float a0 = att[lane];
    float a1 = att[64 + lane];
    // a*lrelu(x) = (0.6a)x + (0.4a)|x|  for slope 0.2
    float c10 = 0.6f * a0, c20 = 0.4f * a0;
    float c11 = 0.6f * a1, c21 = 0.4f * a1;

    float m0 = -INFINITY, m1 = -INFINITY;
    float z0 = 0.f, z1 = 0.f, o0 = 0.f, o1 = 0.f;

    int beg = row_ptr[node];
    int end = row_ptr[node + 1];
    int idx = beg;
    for (; idx + 4 <= end; idx += 4) {
        int s[4];
#pragma unroll
        for (int j = 0; j < 4; ++j) s[j] = colidx[idx + j];
        float l0[4], l1[4], u[4];
#pragma unroll
        for (int j = 0; j < 4; ++j) {
            const float* base = xl + (size_t)s[j] * HC + lane;
            l0[j] = base[0];
            l1[j] = base[64];
        }
#pragma unroll
        for (int j = 0; j < 4; ++j) {
            float x0v = l0[j] + xr0;
            float v0 = fmaf(c10, x0v, c20 * fabsf(x0v));
            float x1v = l1[j] + xr1;
            float v1 = fmaf(c11, x1v, c21 * fabsf(x1v));
            // fold heads into 32-lane halves with a single shuffle
            float ta = lo ? v1 : v0;
            float tb = __shfl_xor(ta, 32, 64);
            u[j] = (lo ? v0 : v1) + tb;
        }
        // level 16 on all four, then pack two edges per register
#pragma unroll
        for (int j = 0; j < 4; ++j) u[j] += __shfl_xor(u[j], 16, 64);
        float wa = g16 ? u[0] : u[1];
        float wb = g16 ? u[2] : u[3];
#pragma unroll
        for (int off = 8; off > 0; off >>= 1) {
            wa += __shfl_xor(wa, off, 64);
            wb += __shfl_xor(wb, off, 64);
        }
        // lanes 0-15:e(0|2),h0  16-31:e(1|3),h0  32-47:e(0|2),h1  48-63:e(1|3),h1
        float L00 = __shfl(wa, 0, 64), L10 = __shfl(wa, 16, 64);
        float L01 = __shfl(wa, 32, 64), L11 = __shfl(wa, 48, 64);
        float L20 = __shfl(wb, 0, 64), L30 = __shfl(wb, 16, 64);
        float L21 = __shfl(wb, 32, 64), L31 = __shfl(wb, 48, 64);

        // batched online softmax: one max-update + one rescale per head per batch
        float bm0 = fmaxf(fmaxf(L00, L10), fmaxf(L20, L30));
        float nm0 = fmaxf(m0, bm0);
        float sc0 = __expf(m0 - nm0);
        float p00 = __expf(L00 - nm0), p10 = __expf(L10 - nm0);
        float p20 = __expf(L20 - nm0), p30 = __expf(L30 - nm0);
        z0 = fmaf(z0, sc0, (p00 + p10) + (p20 + p30));
        o0 = fmaf(o0, sc0, fmaf(p00, l0[0], fmaf(p10, l0[1], fmaf(p20, l0[2], p30 * l0[3]))));
        m0 = nm0;

        float bm1 = fmaxf(fmaxf(L01, L11), fmaxf(L21, L31));
        float nm1 = fmaxf(m1, bm1);
        float sc1 = __expf(m1 - nm1);
        float p01 = __expf(L01 - nm1), p11 = __expf(L11 - nm1);
        float p21 = __expf(L21 - nm1), p31 = __expf(L31 - nm1);
        z1 = fmaf(z1, sc1, (p01 + p11) + (p21 + p31));
        o1 = fmaf(o1, sc1, fmaf(p01, l1[0], fmaf(p11, l1[1], fmaf(p21, l1[2], p31 * l1[3]))));
        m1 = nm1;
    }
    for (; idx < end; ++idx) {
        int s = colidx[idx];
        const float* base = xl + (size_t)s * HC + lane;
        float l0 = base[0];
        float l1 = base[64];
        float x0v = l0 + xr0;
        float v0 = fmaf(c10, x0v, c20 * fabsf(x0v));
        float x1v = l1 + xr1;
        float v1 = fmaf(c11, x1v, c21 * fabsf(x1v));
        float ta = lo ? v1 : v0;
        float tb = __shfl_xor(ta, 32, 64);
        float u = (lo ? v0 : v1) + tb;
#pragma unroll
        for (int off = 16; off > 0; off >>= 1) u += __shfl_xor(u, off, 64);
        float L0 = __shfl(u, 0, 64);
        float L1 = __shfl(u, 32, 64);
        float nm0 = fmaxf(m0, L0);
        float sc0 = __expf(m0 - nm0);
        float p0 = __expf(L0 - nm0);
        z0 = fmaf(z0, sc0, p0);
        o0 = fmaf(o0, sc0, p0 * l0);
        m0 = nm0;
        float nm1 = fmaxf(m1, L1);
        float sc1 = __expf(m1 - nm1);
        float p1 = __expf(L1 - nm1);
        z1 = fmaf(z1, sc1, p1);
        o1 = fmaf(o1, sc1, p1 * l1);
        m1 = nm1;
    }
    float res = 0.5f * (o0 / z0 + o1 / z1) + bias[lane];
    hout[(size_t)node * 64 + lane] = res;
}

// ---------------- GraphNorm stats + coefficient (fused via last-block ticket) ----------------

__global__ __launch_bounds__(256) void colstats_k(const float* __restrict__ h,
                                                  const float* __restrict__ gw,
                                                  const float* __restrict__ gb,
                                                  const float* __restrict__ gm,
                                                  float* __restrict__ stats,
                                                  int* __restrict__ ticket,
                                                  float* __restrict__ cf) {
    int c = threadIdx.x & 63;
    int rg = threadIdx.x >> 6;
    float s = 0.f, s2 = 0.f;
    for (int r = blockIdx.x * 4 + rg; r < NN; r += gridDim.x * 4) {
        float v = h[(size_t)r * 64 + c];
        s += v;
        s2 += v * v;
    }
    __shared__ float b1[4][64];
    __shared__ float b2[4][64];
    b1[rg][c] = s;
    b2[rg][c] = s2;
    __syncthreads();
    if (threadIdx.x < 64) {
        s = b1[0][c] + b1[1][c] + b1[2][c] + b1[3][c];
        s2 = b2[0][c] + b2[1][c] + b2[2][c] + b2[3][c];
        atomicAdd(&stats[c], s);
        atomicAdd(&stats[64 + c], s2);
    }
    __shared__ int lastFlag;
    __threadfence();
    if (threadIdx.x == 0) {
        int t = __hip_atomic_fetch_add(ticket, 1, __ATOMIC_ACQ_REL, __HIP_MEMORY_SCOPE_AGENT);
        lastFlag = (t == (int)gridDim.x - 1);
    }
    __syncthreads();
    if (lastFlag && threadIdx.x < 64) {
        float sum = __hip_atomic_load(&stats[c], __ATOMIC_RELAXED, __HIP_MEMORY_SCOPE_AGENT);
        float sum2 = __hip_atomic_load(&stats[64 + c], __ATOMIC_RELAXED, __HIP_MEMORY_SCOPE_AGENT);
        float inv_n = 1.f / (float)NN;
        float mu = sum * inv_n;
        float ex2 = sum2 * inv_n;
        float g = gm[c];
        float var = ex2 - 2.f * g * mu * mu + g * g * mu * mu;
        float rs = rsqrtf(var + EPSV);
        cf[c] = gw[c] * rs;
        cf[64 + c] = gb[c] - gw[c] * rs * g * mu;
    }
}

__global__ __launch_bounds__(256) void apply_k(const float* __restrict__ h,
                                               const float* __restrict__ cf,
                                               float* __restrict__ y) {
    int i = blockIdx.x * 256 + threadIdx.x;
    if (i >= NN * 64) return;
    int c = i & 63;
    float v = fmaf(cf[c], h[i], cf[64 + c]);
    y[i] = fmaxf(v, 0.f);
}

// ---------------- launch ----------------

extern "C" void kernel_launch(void* const* d_in, const int* in_sizes, int n_in,
                              void* d_out, int out_size, void* d_ws, size_t ws_size,
                              hipStream_t stream) {
    const float* x0 = (const float*)d_in[0];
    const int* ei = (const int*)d_in[1];
    const int* srcp = ei;
    const int* dstp = ei + NE;

    const float* Wl[3], *Wr[3], *att[3], *bv[3], *gw[3], *gb[3], *gm[3];
    for (int l = 0; l < 3; ++l) {
        int base = 2 + 7 * l;
        Wl[l] = (const float*)d_in[base + 0];
        Wr[l] = (const float*)d_in[base + 1];
        att[l] = (const float*)d_in[base + 2];
        bv[l] = (const float*)d_in[base + 3];
        gw[l] = (const float*)d_in[base + 4];
        gb[l] = (const float*)d_in[base + 5];
        gm[l] = (const float*)d_in[base + 6];
    }

    char* p = (char*)d_ws;
    auto take = [&](size_t bytes) -> void* {
        void* r = (void*)p;
        p += (bytes + 255) & ~(size_t)255;
        return r;
    };
    float* xl = (float*)take((size_t)NN * 128 * 4);
    float* xr = (float*)take((size_t)NN * 128 * 4);
    float* hb = (float*)take((size_t)NN * 64 * 4);
    // zero region: stats[3][128] + tickets[3] + cnt[NN]  (single memset)
    size_t zero_bytes = 3 * 128 * 4 + 3 * 4 + (size_t)NN * 4;
    char* zr = (char*)take(zero_bytes);
    float* stats = (float*)zr;                  // 3*128 floats
    int* tickets = (int*)(zr + 3 * 128 * 4);    // 3 ints
    int* cnt = (int*)(zr + 3 * 128 * 4 + 3 * 4);
    int* row_ptr = (int*)take((size_t)(NN + 1) * 4);
    int* fill = (int*)take((size_t)NN * 4);
    int* col = (int*)take((size_t)TE * 4);
    int* aux = (int*)take(64 * 4);
    float* cfb = (float*)take(3 * 128 * 4);

    hipMemsetAsync(zr, 0, zero_bytes, stream);

    int nblk = (NN + 1023) / 1024;
    int egrid = (TE + 255) / 256;
    count_k<<<egrid, 256, 0, stream>>>(dstp, cnt);
    scan1_k<<<nblk, 1024, 0, stream>>>(cnt, row_ptr, aux);
    scan2_k<<<1, 64, 0, stream>>>(aux, nblk);
    scan3_k<<<nblk, 1024, 0, stream>>>(row_ptr, aux, fill);
    scatter_k<<<egrid, 256, 0, stream>>>(srcp, dstp, fill, col);

    int ggrid = (NN + 63) / 64;
    int agrid = (NN + 3) / 4;
    for (int l = 0; l < 3; ++l) {
        float* cf = cfb + l * 128;
        if (l == 0)
            gemm_dual<<<ggrid, 256, 0, stream>>>(x0, Wl[0], Wr[0], xl, xr, NN, 3);
        else
            gemm_fused<<<ggrid, 256, 0, stream>>>(hb, cfb + (l - 1) * 128, Wl[l], Wr[l], xl, xr, NN);
        attn_k<<<agrid, 256, 0, stream>>>(xl, xr, att[l], bv[l], row_ptr, col, hb);
        colstats_k<<<STATS_BLOCKS, 256, 0, stream>>>(hb, gw[l], gb[l], gm[l],
                                                     stats + l * 128, tickets + l, cf);
    }
    apply_k<<<(NN * 64 + 255) / 256, 256, 0, stream>>>(hb, cfb + 2 * 128, (float*)d_out);
}

// Round 4
// 573.246 us; speedup vs baseline: 1.4714x; 1.0308x over previous
//
#include <hip/hip_runtime.h>
#include <math.h>

#define NN 50000
#define NE 800000
#define TE (NE + NN)
#define HC 128
#define NEG_SLOPE 0.2f
#define EPSV 1e-5f
#define STATS_BLOCKS 256

// ---------------- CSR build ----------------

__global__ __launch_bounds__(256) void count_k(const int* __restrict__ dst, int* __restrict__ cnt) {
    int e = blockIdx.x * 256 + threadIdx.x;
    if (e >= TE) return;
    int d = (e < NE) ? dst[e] : (e - NE);
    atomicAdd(&cnt[d], 1);
}

__global__ __launch_bounds__(1024) void scan1_k(const int* __restrict__ cnt,
                                                int* __restrict__ excl,
                                                int* __restrict__ aux) {
    __shared__ int wsum[16];
    int tid = threadIdx.x;
    int gid = blockIdx.x * 1024 + tid;
    int lane = tid & 63, wid = tid >> 6;
    int v = (gid < NN) ? cnt[gid] : 0;
    int x = v;
#pragma unroll
    for (int off = 1; off < 64; off <<= 1) {
        int t = __shfl_up(x, off, 64);
        if (lane >= off) x += t;
    }
    if (lane == 63) wsum[wid] = x;
    __syncthreads();
    if (wid == 0 && lane < 16) {
        int y = wsum[lane];
#pragma unroll
        for (int off = 1; off < 16; off <<= 1) {
            int t = __shfl_up(y, off, 64);
            if (lane >= off) y += t;
        }
        wsum[lane] = y;
    }
    __syncthreads();
    int base = (wid > 0) ? wsum[wid - 1] : 0;
    int incl = base + x;
    if (gid < NN) excl[gid] = incl - v;
    if (tid == 1023) aux[blockIdx.x] = incl;
}

// scan3 with inlined aux-scan (one wave rescans the 49 block totals)
__global__ __launch_bounds__(1024) void scan3_k(int* __restrict__ row_ptr,
                                                const int* __restrict__ aux,
                                                int* __restrict__ fill,
                                                int nblk) {
    __shared__ int base_s;
    if (threadIdx.x < 64) {
        int lane = threadIdx.x;
        int v = (lane < nblk) ? aux[lane] : 0;
        int x = v;
#pragma unroll
        for (int off = 1; off < 64; off <<= 1) {
            int t = __shfl_up(x, off, 64);
            if (lane >= off) x += t;
        }
        if (lane == (int)blockIdx.x) base_s = x - v;  // exclusive prefix at this block
    }
    __syncthreads();
    int gid = blockIdx.x * 1024 + threadIdx.x;
    if (gid < NN) {
        int r = row_ptr[gid] + base_s;
        row_ptr[gid] = r;
        fill[gid] = r;
    }
    if (gid == 0) row_ptr[NN] = TE;
}

// col[] stores BYTE offsets (src * 512) for direct gather addressing
__global__ __launch_bounds__(256) void scatter_k(const int* __restrict__ srcp,
                                                 const int* __restrict__ dstp,
                                                 int* __restrict__ fill,
                                                 int* __restrict__ col) {
    int e = blockIdx.x * 256 + threadIdx.x;
    if (e >= TE) return;
    int s, d;
    if (e < NE) { s = srcp[e]; d = dstp[e]; } else { s = e - NE; d = s; }
    int pos = atomicAdd(&fill[d], 1);
    col[pos] = s << 9;
}

// ---------------- Dual GEMM (layer 1, raw x input) ----------------

__global__ __launch_bounds__(256) void gemm_dual(const float* __restrict__ x,
                                                 const float* __restrict__ Wl,
                                                 const float* __restrict__ Wr,
                                                 float* __restrict__ xl,
                                                 float* __restrict__ xr,
                                                 int n, int K) {
    __shared__ float xs[32][72];
    __shared__ float ws[32][260];
    int tid = threadIdx.x;
    int row0 = blockIdx.x * 64;
    int row_t = (tid >> 5) * 8;
    int c0 = (tid & 31) * 4;

    float acc0[8][4];
    float acc1[8][4];
#pragma unroll
    for (int i = 0; i < 8; ++i)
#pragma unroll
        for (int j = 0; j < 4; ++j) { acc0[i][j] = 0.f; acc1[i][j] = 0.f; }

    for (int k0 = 0; k0 < K; k0 += 32) {
        int kc = min(32, K - k0);
        for (int i = tid; i < 64 * kc; i += 256) {
            int r = i / kc;
            int k = i - r * kc;
            int row = row0 + r;
            xs[k][r] = (row < n) ? x[(size_t)row * K + k0 + k] : 0.f;
        }
        for (int i = tid; i < kc * 64; i += 256) {
            int k = i >> 6;
            int cq = i & 63;
            const float* srcp = (cq < 32) ? &Wl[(size_t)(k0 + k) * 128 + cq * 4]
                                          : &Wr[(size_t)(k0 + k) * 128 + (cq - 32) * 4];
            float4 v = *(const float4*)srcp;
            *(float4*)&ws[k][cq * 4] = v;
        }
        __syncthreads();
        for (int k = 0; k < kc; ++k) {
            float4 a0 = *(float4*)&xs[k][row_t];
            float4 a1 = *(float4*)&xs[k][row_t + 4];
            float4 b0 = *(float4*)&ws[k][c0];
            float4 b1 = *(float4*)&ws[k][c0 + 128];
            float av[8] = {a0.x, a0.y, a0.z, a0.w, a1.x, a1.y, a1.z, a1.w};
            float bl[4] = {b0.x, b0.y, b0.z, b0.w};
            float br[4] = {b1.x, b1.y, b1.z, b1.w};
#pragma unroll
            for (int i = 0; i < 8; ++i)
#pragma unroll
                for (int j = 0; j < 4; ++j) {
                    acc0[i][j] += av[i] * bl[j];
                    acc1[i][j] += av[i] * br[j];
                }
        }
        __syncthreads();
    }
#pragma unroll
    for (int i = 0; i < 8; ++i) {
        int row = row0 + row_t + i;
        if (row < n) {
            float4 o0; o0.x = acc0[i][0]; o0.y = acc0[i][1]; o0.z = acc0[i][2]; o0.w = acc0[i][3];
            float4 o1; o1.x = acc1[i][0]; o1.y = acc1[i][1]; o1.z = acc1[i][2]; o1.w = acc1[i][3];
            *(float4*)&xl[(size_t)row * HC + c0] = o0;
            *(float4*)&xr[(size_t)row * HC + c0] = o1;
        }
    }
}

// ---------------- Dual GEMM with fused graph-norm + ReLU on the input ----------------

__global__ __launch_bounds__(256) void gemm_fused(const float* __restrict__ h,
                                                  const float* __restrict__ cf,
                                                  const float* __restrict__ Wl,
                                                  const float* __restrict__ Wr,
                                                  float* __restrict__ xl,
                                                  float* __restrict__ xr,
                                                  int n) {
    __shared__ float xs[32][72];
    __shared__ float ws[32][260];
    int tid = threadIdx.x;
    int row0 = blockIdx.x * 64;
    int row_t = (tid >> 5) * 8;
    int c0 = (tid & 31) * 4;

    float acc0[8][4];
    float acc1[8][4];
#pragma unroll
    for (int i = 0; i < 8; ++i)
#pragma unroll
        for (int j = 0; j < 4; ++j) { acc0[i][j] = 0.f; acc1[i][j] = 0.f; }

    for (int k0 = 0; k0 < 64; k0 += 32) {
        for (int i = tid; i < 64 * 32; i += 256) {
            int r = i >> 5;
            int k = i & 31;
            int row = row0 + r;
            float v = 0.f;
            if (row < n) {
                v = h[(size_t)row * 64 + k0 + k];
                v = fmaf(cf[k0 + k], v, cf[64 + k0 + k]);
                v = fmaxf(v, 0.f);
            }
            xs[k][r] = v;
        }
        for (int i = tid; i < 32 * 64; i += 256) {
            int k = i >> 6;
            int cq = i & 63;
            const float* srcp = (cq < 32) ? &Wl[(size_t)(k0 + k) * 128 + cq * 4]
                                          : &Wr[(size_t)(k0 + k) * 128 + (cq - 32) * 4];
            float4 v = *(const float4*)srcp;
            *(float4*)&ws[k][cq * 4] = v;
        }
        __syncthreads();
        for (int k = 0; k < 32; ++k) {
            float4 a0 = *(float4*)&xs[k][row_t];
            float4 a1 = *(float4*)&xs[k][row_t + 4];
            float4 b0 = *(float4*)&ws[k][c0];
            float4 b1 = *(float4*)&ws[k][c0 + 128];
            float av[8] = {a0.x, a0.y, a0.z, a0.w, a1.x, a1.y, a1.z, a1.w};
            float bl[4] = {b0.x, b0.y, b0.z, b0.w};
            float br[4] = {b1.x, b1.y, b1.z, b1.w};
#pragma unroll
            for (int i = 0; i < 8; ++i)
#pragma unroll
                for (int j = 0; j < 4; ++j) {
                    acc0[i][j] += av[i] * bl[j];
                    acc1[i][j] += av[i] * br[j];
                }
        }
        __syncthreads();
    }
#pragma unroll
    for (int i = 0; i < 8; ++i) {
        int row = row0 + row_t + i;
        if (row < n) {
            float4 o0; o0.x = acc0[i][0]; o0.y = acc0[i][1]; o0.z = acc0[i][2]; o0.w = acc0[i][3];
            float4 o1; o1.x = acc1[i][0]; o1.y = acc1[i][1]; o1.z = acc1[i][2]; o1.w = acc1[i][3];
            *(float4*)&xl[(size_t)row * HC + c0] = o0;
            *(float4*)&xr[(size_t)row * HC + c0] = o1;
        }
    }
}

// ---------------- Attention ----------------
// One wave per dst node. Lanes 0-31: head0 dims 0-63 (2 dims/lane: lane*4 B and +128 B).
// Lanes 32-63: head1. Reduction within 32-lane halves -> result replicated per half
// = exactly the head each lane needs; no broadcasts. No max-tracking (|logit| << 88).

__global__ __launch_bounds__(256) void attn_k(const float* __restrict__ xl,
                                              const float* __restrict__ xr,
                                              const float* __restrict__ att,
                                              const float* __restrict__ bias,
                                              const int* __restrict__ row_ptr,
                                              const int* __restrict__ coloff,
                                              float* __restrict__ hout) {
    int lane = threadIdx.x & 63;
    int node = blockIdx.x * 4 + (threadIdx.x >> 6);
    if (node >= NN) return;
    int laneh = lane & 31;
    int lanebase = ((lane >> 5) << 8) | (laneh << 2);  // byte offset into a 512B row
    bool b16 = (lane & 16) == 0;

    const char* xlc = (const char*)xl;
    const char* xrc = (const char*)xr;
    unsigned nodeoff = (unsigned)node << 9;

    float xrv1 = *(const float*)(xrc + nodeoff + lanebase);
    float xrv2 = *(const float*)(xrc + nodeoff + lanebase + 128);
    float a1 = att[lanebase >> 2];
    float a2 = att[(lanebase >> 2) + 32];
    float c11 = 0.6f * a1, c21 = 0.4f * a1;
    float c12 = 0.6f * a2, c22 = 0.4f * a2;

    float z = 0.f, o1 = 0.f, o2 = 0.f;

    int beg = row_ptr[node];
    int end = row_ptr[node + 1];
    int idx = beg;
    for (; idx + 8 <= end; idx += 8) {
        int offs[8];
#pragma unroll
        for (int j = 0; j < 8; ++j) offs[j] = coloff[idx + j];
        float l1[8], l2[8], u[8];
#pragma unroll
        for (int j = 0; j < 8; ++j) {
            const char* p = xlc + (unsigned)offs[j] + lanebase;
            l1[j] = *(const float*)p;
            l2[j] = *(const float*)(p + 128);
        }
#pragma unroll
        for (int j = 0; j < 8; ++j) {
            float t1 = l1[j] + xrv1;
            float t2 = l2[j] + xrv2;
            float v = fmaf(c11, t1, c21 * fabsf(t1));
            v = fmaf(c12, t2, v);
            u[j] = fmaf(c22, fabsf(t2), v);
        }
#pragma unroll
        for (int j = 0; j < 8; ++j) u[j] += __shfl_xor(u[j], 16, 64);
        float w0 = b16 ? u[0] : u[1];
        float w1 = b16 ? u[2] : u[3];
        float w2 = b16 ? u[4] : u[5];
        float w3 = b16 ? u[6] : u[7];
#pragma unroll
        for (int off = 8; off > 0; off >>= 1) {
            w0 += __shfl_xor(w0, off, 64);
            w1 += __shfl_xor(w1, off, 64);
            w2 += __shfl_xor(w2, off, 64);
            w3 += __shfl_xor(w3, off, 64);
        }
        float s0 = __shfl_xor(w0, 16, 64);
        float s1 = __shfl_xor(w1, 16, 64);
        float s2 = __shfl_xor(w2, 16, 64);
        float s3 = __shfl_xor(w3, 16, 64);
        float p0 = __expf(b16 ? w0 : s0);
        float p1 = __expf(b16 ? s0 : w0);
        float p2 = __expf(b16 ? w1 : s1);
        float p3 = __expf(b16 ? s1 : w1);
        float p4 = __expf(b16 ? w2 : s2);
        float p5 = __expf(b16 ? s2 : w2);
        float p6 = __expf(b16 ? w3 : s3);
        float p7 = __expf(b16 ? s3 : w3);
        z += ((p0 + p1) + (p2 + p3)) + ((p4 + p5) + (p6 + p7));
        o1 = fmaf(p0, l1[0], o1); o2 = fmaf(p0, l2[0], o2);
        o1 = fmaf(p1, l1[1], o1); o2 = fmaf(p1, l2[1], o2);
        o1 = fmaf(p2, l1[2], o1); o2 = fmaf(p2, l2[2], o2);
        o1 = fmaf(p3, l1[3], o1); o2 = fmaf(p3, l2[3], o2);
        o1 = fmaf(p4, l1[4], o1); o2 = fmaf(p4, l2[4], o2);
        o1 = fmaf(p5, l1[5], o1); o2 = fmaf(p5, l2[5], o2);
        o1 = fmaf(p6, l1[6], o1); o2 = fmaf(p6, l2[6], o2);
        o1 = fmaf(p7, l1[7], o1); o2 = fmaf(p7, l2[7], o2);
    }
    for (; idx < end; ++idx) {
        const char* p = xlc + (unsigned)coloff[idx] + lanebase;
        float l1 = *(const float*)p;
        float l2 = *(const float*)(p + 128);
        float t1 = l1 + xrv1;
        float t2 = l2 + xrv2;
        float v = fmaf(c11, t1, c21 * fabsf(t1));
        v = fmaf(c12, t2, v);
        float u = fmaf(c22, fabsf(t2), v);
#pragma unroll
        for (int off = 16; off > 0; off >>= 1) u += __shfl_xor(u, off, 64);
        float pj = __expf(u);
        z += pj;
        o1 = fmaf(pj, l1, o1);
        o2 = fmaf(pj, l2, o2);
    }
    float zi = 1.0f / z;
    float t1 = o1 * zi;
    float t2 = o2 * zi;
    float u1 = __shfl_xor(t1, 32, 64);
    float u2 = __shfl_xor(t2, 32, 64);
    if (lane < 32) {
        float r1 = fmaf(0.5f, t1 + u1, bias[laneh]);
        float r2 = fmaf(0.5f, t2 + u2, bias[laneh + 32]);
        float* q = hout + (size_t)node * 64 + laneh;
        q[0] = r1;
        q[32] = r2;
    }
}

// ---------------- GraphNorm stats + coefficient (fused via last-block ticket) ----------------

__global__ __launch_bounds__(256) void colstats_k(const float* __restrict__ h,
                                                  const float* __restrict__ gw,
                                                  const float* __restrict__ gb,
                                                  const float* __restrict__ gm,
                                                  float* __restrict__ stats,
                                                  int* __restrict__ ticket,
                                                  float* __restrict__ cf) {
    int c = threadIdx.x & 63;
    int rg = threadIdx.x >> 6;
    float s = 0.f, s2 = 0.f;
    for (int r = blockIdx.x * 4 + rg; r < NN; r += gridDim.x * 4) {
        float v = h[(size_t)r * 64 + c];
        s += v;
        s2 += v * v;
    }
    __shared__ float b1[4][64];
    __shared__ float b2[4][64];
    b1[rg][c] = s;
    b2[rg][c] = s2;
    __syncthreads();
    if (threadIdx.x < 64) {
        s = b1[0][c] + b1[1][c] + b1[2][c] + b1[3][c];
        s2 = b2[0][c] + b2[1][c] + b2[2][c] + b2[3][c];
        atomicAdd(&stats[c], s);
        atomicAdd(&stats[64 + c], s2);
    }
    __shared__ int lastFlag;
    __threadfence();
    if (threadIdx.x == 0) {
        int t = __hip_atomic_fetch_add(ticket, 1, __ATOMIC_ACQ_REL, __HIP_MEMORY_SCOPE_AGENT);
        lastFlag = (t == (int)gridDim.x - 1);
    }
    __syncthreads();
    if (lastFlag && threadIdx.x < 64) {
        float sum = __hip_atomic_load(&stats[c], __ATOMIC_RELAXED, __HIP_MEMORY_SCOPE_AGENT);
        float sum2 = __hip_atomic_load(&stats[64 + c], __ATOMIC_RELAXED, __HIP_MEMORY_SCOPE_AGENT);
        float inv_n = 1.f / (float)NN;
        float mu = sum * inv_n;
        float ex2 = sum2 * inv_n;
        float g = gm[c];
        float var = ex2 - 2.f * g * mu * mu + g * g * mu * mu;
        float rs = rsqrtf(var + EPSV);
        cf[c] = gw[c] * rs;
        cf[64 + c] = gb[c] - gw[c] * rs * g * mu;
    }
}

__global__ __launch_bounds__(256) void apply_k(const float* __restrict__ h,
                                               const float* __restrict__ cf,
                                               float* __restrict__ y) {
    int i = blockIdx.x * 256 + threadIdx.x;
    if (i >= NN * 64) return;
    int c = i & 63;
    float v = fmaf(cf[c], h[i], cf[64 + c]);
    y[i] = fmaxf(v, 0.f);
}

// ---------------- launch ----------------

extern "C" void kernel_launch(void* const* d_in, const int* in_sizes, int n_in,
                              void* d_out, int out_size, void* d_ws, size_t ws_size,
                              hipStream_t stream) {
    const float* x0 = (const float*)d_in[0];
    const int* ei = (const int*)d_in[1];
    const int* srcp = ei;
    const int* dstp = ei + NE;

    const float* Wl[3], *Wr[3], *att[3], *bv[3], *gw[3], *gb[3], *gm[3];
    for (int l = 0; l < 3; ++l) {
        int base = 2 + 7 * l;
        Wl[l] = (const float*)d_in[base + 0];
        Wr[l] = (const float*)d_in[base + 1];
        att[l] = (const float*)d_in[base + 2];
        bv[l] = (const float*)d_in[base + 3];
        gw[l] = (const float*)d_in[base + 4];
        gb[l] = (const float*)d_in[base + 5];
        gm[l] = (const float*)d_in[base + 6];
    }

    char* p = (char*)d_ws;
    auto take = [&](size_t bytes) -> void* {
        void* r = (void*)p;
        p += (bytes + 255) & ~(size_t)255;
        return r;
    };
    float* xl = (float*)take((size_t)NN * 128 * 4);
    float* xr = (float*)take((size_t)NN * 128 * 4);
    float* hb = (float*)take((size_t)NN * 64 * 4);
    size_t zero_bytes = 3 * 128 * 4 + 3 * 4 + (size_t)NN * 4;
    char* zr = (char*)take(zero_bytes);
    float* stats = (float*)zr;
    int* tickets = (int*)(zr + 3 * 128 * 4);
    int* cnt = (int*)(zr + 3 * 128 * 4 + 3 * 4);
    int* row_ptr = (int*)take((size_t)(NN + 1) * 4);
    int* fill = (int*)take((size_t)NN * 4);
    int* col = (int*)take((size_t)TE * 4);
    int* aux = (int*)take(64 * 4);
    float* cfb = (float*)take(3 * 128 * 4);

    hipMemsetAsync(zr, 0, zero_bytes, stream);

    int nblk = (NN + 1023) / 1024;
    int egrid = (TE + 255) / 256;
    count_k<<<egrid, 256, 0, stream>>>(dstp, cnt);
    scan1_k<<<nblk, 1024, 0, stream>>>(cnt, row_ptr, aux);
    scan3_k<<<nblk, 1024, 0, stream>>>(row_ptr, aux, fill, nblk);
    scatter_k<<<egrid, 256, 0, stream>>>(srcp, dstp, fill, col);

    int ggrid = (NN + 63) / 64;
    int agrid = (NN + 3) / 4;
    for (int l = 0; l < 3; ++l) {
        float* cf = cfb + l * 128;
        if (l == 0)
            gemm_dual<<<ggrid, 256, 0, stream>>>(x0, Wl[0], Wr[0], xl, xr, NN, 3);
        else
            gemm_fused<<<ggrid, 256, 0, stream>>>(hb, cfb + (l - 1) * 128, Wl[l], Wr[l], xl, xr, NN);
        attn_k<<<agrid, 256, 0, stream>>>(xl, xr, att[l], bv[l], row_ptr, col, hb);
        colstats_k<<<STATS_BLOCKS, 256, 0, stream>>>(hb, gw[l], gb[l], gm[l],
                                                     stats + l * 128, tickets + l, cf);
    }
    apply_k<<<(NN * 64 + 255) / 256, 256, 0, stream>>>(hb, cfb + 2 * 128, (float*)d_out);
}